// Round 14
// baseline (622.290 us; speedup 1.0000x reference)
//
#include <hip/hip_runtime.h>
#include <hip/hip_fp16.h>

#define NNODE 10000
#define NEDGE 160000
#define W32 32
#define BSTR 40          // f16 row stride for B panels (80 B, 16B-aligned)
#define PANEL_F16 10240  // h2 panels: 256 cols * 40
#define PANEL3_F16 5120  // msg panels: 128 cols * 40
#define HB_STR 264       // hbuf f16 stride
#define TB_STR 1036      // tgen tile f16 stride

typedef _Float16 f16;
typedef _Float16 f16x4 __attribute__((ext_vector_type(4)));
typedef _Float16 f16x8 __attribute__((ext_vector_type(8)));
typedef float f32x4 __attribute__((ext_vector_type(4)));

// ---- stage one 20480-B panel (1280 slots) with 4 waves (256 thr) ----
__device__ __forceinline__ void stage_panel(f16* lds, const f16* g, int w, int lane) {
    #pragma unroll
    for (int i = 0; i < 5; ++i) {
        int slot = w * 320 + i * 64 + lane;
        __builtin_amdgcn_global_load_lds(
            (const __attribute__((address_space(1))) unsigned int*)(g + (size_t)slot * 8),
            (__attribute__((address_space(3))) unsigned int*)(lds + (size_t)(w * 320 + i * 64) * 8),
            16, 0, 0);
    }
}

// ---- stage one 10240-B panel (640 slots): 4 waves (fallback msg_fused) ----
__device__ __forceinline__ void stage_panel10k(f16* lds, const f16* g, int w, int lane) {
    #pragma unroll
    for (int i = 0; i < 2; ++i) {
        int base = i * 256 + w * 64;
        __builtin_amdgcn_global_load_lds(
            (const __attribute__((address_space(1))) unsigned int*)(g + (size_t)(base + lane) * 8),
            (__attribute__((address_space(3))) unsigned int*)(lds + (size_t)base * 8),
            16, 0, 0);
    }
    if (w < 2) {
        int base = 512 + w * 64;
        __builtin_amdgcn_global_load_lds(
            (const __attribute__((address_space(1))) unsigned int*)(g + (size_t)(base + lane) * 8),
            (__attribute__((address_space(3))) unsigned int*)(lds + (size_t)base * 8),
            16, 0, 0);
    }
}

// ================= weight packs =================
__global__ __launch_bounds__(256) void pack_k1(const float* __restrict__ k1w, f16* __restrict__ k1p) {
    int t = blockIdx.x * 256 + threadIdx.x;           // 10240
    int j = t / BSTR, c = t % BSTR;
    k1p[t] = (c < 6) ? (f16)k1w[c * 256 + j] : (f16)0.f;
}
__global__ __launch_bounds__(256) void pack_k2(const float* __restrict__ k2w, f16* __restrict__ k2p) {
    int t = blockIdx.x * 256 + threadIdx.x;           // 8*10240
    int kk = t / PANEL_F16, r = t % PANEL_F16;
    int j = r / BSTR, c = r % BSTR;
    k2p[t] = (c < 32) ? (f16)k2w[(size_t)(kk * 32 + c) * 256 + j] : (f16)0.f;
}
// fallback: k3 panels of 128 cols
__global__ __launch_bounds__(256) void pack_k3(const float* __restrict__ k3w, f16* __restrict__ k3p) {
    int t = blockIdx.x * 256 + threadIdx.x;           // 64*5120
    int p = t / PANEL3_F16, r = t % PANEL3_F16;
    int np = p >> 3, kk = p & 7;
    int j = r / BSTR, c = r % BSTR;
    k3p[t] = (c < 32) ? (f16)k3w[(size_t)(kk * 32 + c) * 1024 + np * 128 + j] : (f16)0.f;
}
// T-path: k3t[q'][i] = k3[c][i*32+o] with q' = o*256 + c  (8192 rows x BSTR)
__global__ __launch_bounds__(256) void pack_k3t(const float* __restrict__ k3w, f16* __restrict__ k3t) {
    int t = blockIdx.x * 256 + threadIdx.x;           // 327680
    int q = t / BSTR, i = t % BSTR;
    int o = q >> 8, c = q & 255;
    k3t[t] = (i < 32) ? (f16)k3w[(size_t)c * 1024 + i * 32 + o] : (f16)0.f;
}

// ================= h2 = relu(relu(ea@k1+b1)@k2+b2), fp16 out =================
// v6 (round-10 proven): dbuf panels + scattered epilogue + layer-2 wave-pair split.
__global__ __launch_bounds__(256) void h2_kernel(
    const float* __restrict__ ea,
    const f16* __restrict__ k1p, const float* __restrict__ k1b,
    const f16* __restrict__ k2p, const float* __restrict__ k2b,
    f16* __restrict__ h2c, int e_start, const int* __restrict__ remap)
{
    __shared__ __align__(16) f16 bls[2][256 * BSTR];  // 40 KB
    __shared__ __align__(16) f16 ea_s[64 * BSTR];     // 5 KB
    __shared__ __align__(16) f16 hbuf[64 * HB_STR];   // 33 KB -> 78 KB total, 2 blocks/CU

    const int t = threadIdx.x, w = t >> 6, lane = t & 63, quad = lane >> 4, l15 = lane & 15;
    const int el0 = blockIdx.x * 64;
    const int e0 = e_start + el0;

    stage_panel(bls[0], k1p, w, lane);                // k1 panel into b0
    for (int i = t; i < 64 * BSTR; i += 256) {
        int e = i / BSTR, c = i % BSTR;
        ea_s[i] = (f16)((c < 6) ? ea[(size_t)(e0 + e) * 6 + c] : 0.f);
    }
    __syncthreads();                                  // b0 + ea_s ready

    // ---- layer 1: wave w owns rows w*16..+15, all 256 cols ----
    f16x8 a1 = *(const f16x8*)&ea_s[(w * 16 + l15) * BSTR + quad * 8];
    {
        f32x4 acc1[16];
        #pragma unroll
        for (int nt = 0; nt < 16; ++nt) { float b = k1b[nt * 16 + l15]; acc1[nt] = (f32x4){b, b, b, b}; }
        stage_panel(bls[1], k2p, w, lane);            // k2 panel 0 into b1 (overlaps k1 MFMAs)
        #pragma unroll
        for (int nt = 0; nt < 16; ++nt) {
            f16x8 bf = *(const f16x8*)&bls[0][(nt * 16 + l15) * BSTR + quad * 8];
            acc1[nt] = __builtin_amdgcn_mfma_f32_16x16x32_f16(a1, bf, acc1[nt], 0, 0, 0);
        }
        #pragma unroll
        for (int nt = 0; nt < 16; ++nt)
            #pragma unroll
            for (int r = 0; r < 4; ++r)
                hbuf[(w * 16 + quad * 4 + r) * HB_STR + nt * 16 + l15] = (f16)fmaxf(acc1[nt][r], 0.f);
    }
    __syncthreads();                                  // hbuf (all rows) + b1 ready; b0 free

    // ---- layer 2: wave w -> row-half mh = w&1 (32 rows), col-half nh = w>>1 (128 cols) ----
    const int mh = w & 1, nh = w >> 1;
    f16x8 a2[2][8];
    #pragma unroll
    for (int m = 0; m < 2; ++m)
        #pragma unroll
        for (int kk = 0; kk < 8; ++kk)
            a2[m][kk] = *(const f16x8*)&hbuf[(mh * 32 + m * 16 + l15) * HB_STR + kk * 32 + quad * 8];
    f32x4 acc[2][8];
    #pragma unroll
    for (int nt = 0; nt < 8; ++nt) {
        float b = k2b[nh * 128 + nt * 16 + l15];
        acc[0][nt] = (f32x4){b, b, b, b};
        acc[1][nt] = (f32x4){b, b, b, b};
    }
    for (int kk = 0; kk < 8; ++kk) {
        if (kk < 7)
            stage_panel(bls[kk & 1], k2p + (size_t)(kk + 1) * PANEL_F16, w, lane);
        const f16* B = bls[(kk + 1) & 1];             // panel kk
        #pragma unroll
        for (int nt = 0; nt < 8; ++nt) {
            f16x8 bf = *(const f16x8*)&B[(nh * 128 + nt * 16 + l15) * BSTR + quad * 8];
            acc[0][nt] = __builtin_amdgcn_mfma_f32_16x16x32_f16(a2[0][kk], bf, acc[0][nt], 0, 0, 0);
            acc[1][nt] = __builtin_amdgcn_mfma_f32_16x16x32_f16(a2[1][kk], bf, acc[1][nt], 0, 0, 0);
        }
        __syncthreads();
    }
    size_t orow[2][4];
    #pragma unroll
    for (int m = 0; m < 2; ++m)
        #pragma unroll
        for (int r = 0; r < 4; ++r) {
            int row = mh * 32 + m * 16 + quad * 4 + r;
            orow[m][r] = remap ? (size_t)remap[e0 + row] : (size_t)(el0 + row);
        }
    #pragma unroll
    for (int m = 0; m < 2; ++m)
        #pragma unroll
        for (int nt = 0; nt < 8; ++nt)
            #pragma unroll
            for (int r = 0; r < 4; ++r)
                h2c[orow[m][r] * 256 + nh * 128 + nt * 16 + l15] = (f16)fmaxf(acc[m][nt][r], 0.f);
}

// ================= sort by src (counting sort) =================
__global__ __launch_bounds__(256) void hist_kernel(const int* __restrict__ ei, int* __restrict__ cnt) {
    int e = blockIdx.x * 256 + threadIdx.x;
    if (e < NEDGE) atomicAdd(&cnt[ei[e]], 1);
}
__global__ __launch_bounds__(256) void scan_kernel(
    const int* __restrict__ cnt, int* __restrict__ edgeStart, int* __restrict__ cursor)
{
    __shared__ int pE[256];
    const int t = threadIdx.x;
    int se = 0;
    for (int k = 0; k < 40; ++k) {
        int n = t * 40 + k;
        if (n < NNODE) se += cnt[n];
    }
    pE[t] = se;
    __syncthreads();
    if (t == 0) {
        int aE = 0;
        for (int i = 0; i < 256; ++i) { int tE = pE[i]; pE[i] = aE; aE += tE; }
    }
    __syncthreads();
    int oE = pE[t];
    for (int k = 0; k < 40; ++k) {
        int n = t * 40 + k;
        if (n < NNODE) {
            edgeStart[n] = oE; cursor[n] = oE;
            oE += cnt[n];
        }
    }
}
__global__ __launch_bounds__(256) void scatter_kernel(
    const int* __restrict__ ei, int* __restrict__ cursor,
    int* __restrict__ dstS, int* __restrict__ sortpos)
{
    int e = blockIdx.x * 256 + threadIdx.x;
    if (e < NEDGE) {
        int s = ei[e];
        int p = atomicAdd(&cursor[s], 1);
        dstS[p] = ei[NEDGE + e];
        sortpos[e] = p;
    }
}

// ================= T-path per depth =================
// h0 + fused Bb: h[n,j] = x[n]*w[j]+b[j]; Bb[n,o] = sum_i h[n,i]*k3b[i*32+o]
__global__ __launch_bounds__(256) void h0_kernel(
    const float* __restrict__ x, const float* __restrict__ fc1w,
    const float* __restrict__ fc1b, float* __restrict__ h,
    const float* __restrict__ k3b, float* __restrict__ Bb)
{
    int idx = blockIdx.x * 256 + threadIdx.x;
    int n = idx >> 5, j = idx & 31;
    float hv = x[n] * fc1w[j] + fc1b[j];
    h[idx] = hv;
    float s = 0.f;
    #pragma unroll
    for (int i = 0; i < 32; ++i)
        s += __shfl(hv, i, 32) * k3b[i * 32 + j];
    Bb[idx] = s;
}

// Tt[(n-n0)][q'] = sum_i h[n,i] * k3t[q'][i] (round-6 proven version)
__global__ __launch_bounds__(256) void tgen_kernel(
    const float* __restrict__ h, const f16* __restrict__ k3t, f16* __restrict__ Tt,
    int n0, int n1)
{
    __shared__ __align__(16) f16 tbuf[16 * TB_STR];   // 33 KB

    const int t = threadIdx.x, w = t >> 6, lane = t & 63, quad = lane >> 4, l15 = lane & 15;
    const int nBase = n0 + blockIdx.x * 16;
    const int colBase = blockIdx.y * 1024;

    f16x8 a;
    #pragma unroll
    for (int i = 0; i < 8; ++i) a[i] = (f16)0.f;
    int node = nBase + l15;
    if (node < n1) {
        const float4* hp = (const float4*)(h + (size_t)node * 32) + quad * 2;
        float4 v0 = hp[0], v1 = hp[1];
        a[0] = (f16)v0.x; a[1] = (f16)v0.y; a[2] = (f16)v0.z; a[3] = (f16)v0.w;
        a[4] = (f16)v1.x; a[5] = (f16)v1.y; a[6] = (f16)v1.z; a[7] = (f16)v1.w;
    }
    f32x4 acc[16];
    #pragma unroll
    for (int nt = 0; nt < 16; ++nt) {
        f16x8 bf = *(const f16x8*)&k3t[(size_t)(colBase + w * 256 + nt * 16 + l15) * BSTR + quad * 8];
        acc[nt] = __builtin_amdgcn_mfma_f32_16x16x32_f16(a, bf, (f32x4){0.f, 0.f, 0.f, 0.f}, 0, 0, 0);
    }
    #pragma unroll
    for (int nt = 0; nt < 16; ++nt)
        #pragma unroll
        for (int r = 0; r < 4; ++r)
            tbuf[(quad * 4 + r) * TB_STR + w * 256 + nt * 16 + l15] = (f16)acc[nt][r];
    __syncthreads();
    {
        const int row = t >> 4, u = t & 15;
        const int nd = nBase + row;
        if (nd < n1) {
            f16* gdst = Tt + (size_t)(nd - n0) * 8192 + colBase;
            const f16* lsrc = &tbuf[row * TB_STR];
            #pragma unroll
            for (int j = 0; j < 8; ++j) {
                int p = u + 16 * j;
                *(f16x8*)(gdst + p * 8) = *(const f16x8*)(lsrc + p * 8);
            }
        }
    }
}

// per-NODE MFMA contraction: one wave per node; B-fragments of T[n] loaded ONCE
// into registers (bf[2][8] = 64 VGPR), reused across all 16-edge groups of the node.
__global__ __launch_bounds__(256) void msgT_kernel(
    const f16* __restrict__ h2s, const f16* __restrict__ Tt, const float* __restrict__ Bb,
    const int* __restrict__ cnt, const int* __restrict__ edgeStart,
    const int* __restrict__ dstS, float* __restrict__ agg,
    int n0, int n1)
{
    const int t = threadIdx.x, w = t >> 6, lane = t & 63, quad = lane >> 4, l15 = lane & 15;
    const int gw = blockIdx.x * 4 + w, nw = gridDim.x * 4;
    for (int n = n0 + gw; n < n1; n += nw) {
        const int deg = cnt[n];
        if (deg == 0) continue;
        const int e0 = edgeStart[n];
        const f16* Tn = Tt + (size_t)(n - n0) * 8192;
        f16x8 bf[2][8];
        #pragma unroll
        for (int nt = 0; nt < 2; ++nt)
            #pragma unroll
            for (int kk = 0; kk < 8; ++kk)
                bf[nt][kk] = *(const f16x8*)&Tn[(nt * 16 + l15) * 256 + kk * 32 + quad * 8];
        const float b0 = Bb[n * 32 + l15], b1 = Bb[n * 32 + 16 + l15];
        for (int eb = 0; eb < deg; eb += 16) {
            const int c = (deg - eb < 16) ? (deg - eb) : 16;
            f32x4 acc0 = (f32x4){b0, b0, b0, b0};
            f32x4 acc1 = (f32x4){b1, b1, b1, b1};
            #pragma unroll
            for (int kk = 0; kk < 8; ++kk) {
                f16x8 a;
                #pragma unroll
                for (int i = 0; i < 8; ++i) a[i] = (f16)0.f;
                if (l15 < c)
                    a = *(const f16x8*)&h2s[(size_t)(e0 + eb + l15) * 256 + kk * 32 + quad * 8];
                acc0 = __builtin_amdgcn_mfma_f32_16x16x32_f16(a, bf[0][kk], acc0, 0, 0, 0);
                acc1 = __builtin_amdgcn_mfma_f32_16x16x32_f16(a, bf[1][kk], acc1, 0, 0, 0);
            }
            #pragma unroll
            for (int r = 0; r < 4; ++r) {
                int er = quad * 4 + r;
                if (er < c) {
                    int d = dstS[e0 + eb + er];
                    atomicAdd(&agg[(size_t)d * 32 + l15],      acc0[r]);
                    atomicAdd(&agg[(size_t)d * 32 + 16 + l15], acc1[r]);
                }
            }
        }
    }
}

// ========== fallback: fused W-recompute + contract + scatter ==========
__global__ __launch_bounds__(256, 2) void msg_fused(
    const int* __restrict__ ei, const f16* __restrict__ h2c,
    const f16* __restrict__ k3p, const float* __restrict__ k3b,
    const float* __restrict__ h, float* __restrict__ agg, int e_start)
{
    __shared__ __align__(16) f16 bls[2][PANEL3_F16];
    __shared__ __align__(16) f16 h_s[256 * 36];
    __shared__ int dst_s[256];

    const int t = threadIdx.x, w = t >> 6, lane = t & 63, quad = lane >> 4, l15 = lane & 15;
    const int el0 = blockIdx.x * 256;
    const int e0 = e_start + el0;

    dst_s[t] = ei[NEDGE + e0 + t];
    {
        int srcn = ei[e0 + t];
        const float4* hr = (const float4*)(h + (size_t)srcn * 32);
        f16* dp = &h_s[t * 36];
        #pragma unroll
        for (int qq = 0; qq < 8; ++qq) {
            float4 v = hr[qq];
            dp[qq * 4 + 0] = (f16)v.x; dp[qq * 4 + 1] = (f16)v.y;
            dp[qq * 4 + 2] = (f16)v.z; dp[qq * 4 + 3] = (f16)v.w;
        }
    }
    stage_panel10k(bls[0], k3p, w, lane);

    float msg[4][4][2];
    #pragma unroll
    for (int m = 0; m < 4; ++m)
        #pragma unroll
        for (int r = 0; r < 4; ++r) { msg[m][r][0] = 0.f; msg[m][r][1] = 0.f; }

    f32x4 acc[4][8];
    __syncthreads();

    for (int it = 0; it < 64; ++it) {
        const int np = it >> 3, kk = it & 7;
        if (it) __syncthreads();
        if (it < 63) stage_panel10k(bls[(it + 1) & 1], k3p + (size_t)(it + 1) * PANEL3_F16, w, lane);

        f16x8 a[4];
        #pragma unroll
        for (int m = 0; m < 4; ++m)
            a[m] = *(const f16x8*)(h2c + (size_t)(el0 + w * 64 + m * 16 + l15) * 256 + kk * 32 + quad * 8);

        if (kk == 0) {
            #pragma unroll
            for (int nt = 0; nt < 8; ++nt) {
                float b = k3b[np * 128 + nt * 16 + l15];
                #pragma unroll
                for (int m = 0; m < 4; ++m) acc[m][nt] = (f32x4){b, b, b, b};
            }
        }
        const f16* B = bls[it & 1];
        #pragma unroll
        for (int nt = 0; nt < 8; ++nt) {
            f16x8 bf = *(const f16x8*)&B[(nt * 16 + l15) * BSTR + quad * 8];
            #pragma unroll
            for (int m = 0; m < 4; ++m)
                acc[m][nt] = __builtin_amdgcn_mfma_f32_16x16x32_f16(a[m], bf, acc[m][nt], 0, 0, 0);
        }
        if (kk == 7) {
            #pragma unroll
            for (int m = 0; m < 4; ++m)
                #pragma unroll
                for (int r = 0; r < 4; ++r) {
                    int row = w * 64 + m * 16 + quad * 4 + r;
                    f16x4 h4 = *(const f16x4*)&h_s[row * 36 + np * 4];
                    #pragma unroll
                    for (int nt = 0; nt < 8; ++nt)
                        msg[m][r][nt & 1] += (float)h4[nt >> 1] * acc[m][nt][r];
                }
        }
    }
    #pragma unroll
    for (int m = 0; m < 4; ++m)
        #pragma unroll
        for (int r = 0; r < 4; ++r) {
            int d = dst_s[w * 64 + m * 16 + quad * 4 + r];
            atomicAdd(&agg[d * W32 + l15],      msg[m][r][0]);
            atomicAdd(&agg[d * W32 + 16 + l15], msg[m][r][1]);
        }
}

// ================= small kernels =================
__global__ __launch_bounds__(256) void deg_kernel(
    const int* __restrict__ ei, float* __restrict__ deg)
{
    int e = blockIdx.x * 256 + threadIdx.x;
    if (e < NEDGE) atomicAdd(&deg[ei[NEDGE + e]], 1.f);
}

// update + fused Bb for the NEXT depth
__global__ __launch_bounds__(256) void update_kernel(
    const float* __restrict__ h_old, float* __restrict__ h_new,
    float* __restrict__ agg, const float* __restrict__ deg,
    const float* __restrict__ rootw, const float* __restrict__ convb,
    const float* __restrict__ k3b, float* __restrict__ Bb)
{
    __shared__ float rw[W32][W32 + 1];
    const int t = threadIdx.x;
    for (int q = t; q < W32 * W32; q += 256)
        rw[q >> 5][q & 31] = rootw[q];
    __syncthreads();
    const int nl = t >> 5, j = t & 31;
    const int n = blockIdx.x * 8 + nl;
    float hv = h_old[n * W32 + j];
    float acc = convb[j];
    #pragma unroll
    for (int k = 0; k < W32; ++k)
        acc += __shfl(hv, k, 32) * rw[k][j];
    float inv = 1.f / fmaxf(deg[n], 1.f);
    int idx = n * W32 + j;
    float a = agg[idx];
    agg[idx] = 0.f;
    float hn = fmaxf(a * inv + acc, 0.f);
    h_new[idx] = hn;
    float s = 0.f;
    #pragma unroll
    for (int i = 0; i < 32; ++i)
        s += __shfl(hn, i, 32) * k3b[i * 32 + j];
    Bb[idx] = s;
}

// fallback update (no Bb fusion)
__global__ __launch_bounds__(256) void update_fb_kernel(
    const float* __restrict__ h_old, float* __restrict__ h_new,
    float* __restrict__ agg, const float* __restrict__ deg,
    const float* __restrict__ rootw, const float* __restrict__ convb)
{
    __shared__ float rw[W32][W32 + 1];
    const int t = threadIdx.x;
    for (int q = t; q < W32 * W32; q += 256)
        rw[q >> 5][q & 31] = rootw[q];
    __syncthreads();
    const int nl = t >> 5, j = t & 31;
    const int n = blockIdx.x * 8 + nl;
    float hv = h_old[n * W32 + j];
    float acc = convb[j];
    #pragma unroll
    for (int k = 0; k < W32; ++k)
        acc += __shfl(hv, k, 32) * rw[k][j];
    float inv = 1.f / fmaxf(deg[n], 1.f);
    int idx = n * W32 + j;
    float a = agg[idx];
    agg[idx] = 0.f;
    h_new[idx] = fmaxf(a * inv + acc, 0.f);
}

__global__ __launch_bounds__(256) void out_kernel(
    const float* __restrict__ h, const float* __restrict__ fc2w,
    const float* __restrict__ fc2b, float* __restrict__ out)
{
    int n = blockIdx.x * 256 + threadIdx.x;
    if (n < NNODE) {
        float a = fc2b[0];
        #pragma unroll
        for (int j = 0; j < W32; ++j)
            a += h[n * W32 + j] * fc2w[j];
        out[n] = a;
    }
}

static inline size_t pad256(size_t x) { return (x + 255) & ~(size_t)255; }

extern "C" void kernel_launch(void* const* d_in, const int* in_sizes, int n_in,
                              void* d_out, int out_size, void* d_ws, size_t ws_size,
                              hipStream_t stream) {
    const float* x    = (const float*)d_in[0];
    const int*   ei   = (const int*)  d_in[1];
    const float* ea   = (const float*)d_in[2];
    const float* fc1w = (const float*)d_in[3];
    const float* fc1b = (const float*)d_in[4];
    const float* k1w  = (const float*)d_in[5];
    const float* k1b  = (const float*)d_in[6];
    const float* k2w  = (const float*)d_in[7];
    const float* k2b  = (const float*)d_in[8];
    const float* k3w  = (const float*)d_in[9];
    const float* k3b  = (const float*)d_in[10];
    const float* rootw= (const float*)d_in[11];
    const float* convb= (const float*)d_in[12];
    const float* fc2w = (const float*)d_in[13];
    const float* fc2b = (const float*)d_in[14];
    float* out = (float*)d_out;

    const size_t hbytes = (size_t)NNODE * W32 * 4;
    char* ws = (char*)d_ws;
    size_t off = 0;
    float* hA  = (float*)(ws + off); off += hbytes;
    float* hB  = (float*)(ws + off); off += hbytes;
    float* agg = (float*)(ws + off); off += hbytes;
    float* deg = (float*)(ws + off); off += 40960;
    f16*  k1p  = (f16*)(ws + off);   off += 20480;
    f16*  k2p  = (f16*)(ws + off);   off += 163840;
    f16*  k3p  = (f16*)(ws + off);   off += 655360;
    const size_t fixed = off;

    // ---- T-path layout ----
    size_t toff = fixed;
    f16*  k3t      = (f16*)(ws + toff);  toff += pad256(8192 * BSTR * 2);
    int*  dstS     = (int*)(ws + toff);  toff += pad256((size_t)NEDGE * 4);
    int*  sortpos  = (int*)(ws + toff);  toff += pad256((size_t)NEDGE * 4);
    int*  cnt      = (int*)(ws + toff);  toff += pad256((size_t)NNODE * 4);
    int*  edgeStart= (int*)(ws + toff);  toff += pad256((size_t)NNODE * 4);
    int*  cursor   = (int*)(ws + toff);  toff += pad256((size_t)NNODE * 4);
    float* Bb      = (float*)(ws + toff); toff += pad256((size_t)NNODE * 32 * 4);
    f16*  h2s      = (f16*)(ws + toff);  toff += pad256((size_t)NEDGE * 256 * 2);
    f16*  Tt       = (f16*)(ws + toff);

    // nc=1 preferred (round-3/4 A/B: Tt+h2s fits L3; splitting regressed)
    int nc = 0, CS = 0;
    {
        const int cands[4] = {1, 2, 4, 8};
        for (int ci = 0; ci < 4; ++ci) {
            int c = cands[ci];
            int cs = ((NNODE + c - 1) / c + 15) & ~15;
            size_t tb = (size_t)cs * 8192 * 2;
            if (ws_size >= toff + tb) { nc = c; CS = cs; break; }
        }
    }

    hipMemsetAsync(deg, 0, (size_t)NNODE * 4, stream);
    hipMemsetAsync(agg, 0, (size_t)NNODE * W32 * 4, stream);

    pack_k1<<<40, 256, 0, stream>>>(k1w, k1p);
    pack_k2<<<320, 256, 0, stream>>>(k2w, k2p);

    h0_kernel<<<NNODE * W32 / 256, 256, 0, stream>>>(x, fc1w, fc1b, hA, k3b, Bb);
    deg_kernel<<<(NEDGE + 255) / 256, 256, 0, stream>>>(ei, deg);

    float* hcur = hA; float* hnext = hB;

    if (nc) {
        // ================= T-path =================
        pack_k3t<<<1280, 256, 0, stream>>>(k3w, k3t);
        hipMemsetAsync(cnt, 0, (size_t)NNODE * 4, stream);
        hist_kernel<<<(NEDGE + 255) / 256, 256, 0, stream>>>(ei, cnt);
        scan_kernel<<<1, 256, 0, stream>>>(cnt, edgeStart, cursor);
        scatter_kernel<<<(NEDGE + 255) / 256, 256, 0, stream>>>(ei, cursor, dstS, sortpos);
        h2_kernel<<<NEDGE / 64, 256, 0, stream>>>(ea, k1p, k1b, k2p, k2b, h2s, 0, sortpos);

        for (int d = 0; d < 4; ++d) {
            // Bb for this depth was produced by h0 (d=0) or the previous update (d>0)
            for (int ct = 0; ct < nc; ++ct) {
                int n0 = ct * CS;
                if (n0 >= NNODE) break;
                int n1 = n0 + CS; if (n1 > NNODE) n1 = NNODE;
                dim3 tg((n1 - n0 + 15) / 16, 8);
                tgen_kernel<<<tg, 256, 0, stream>>>(hcur, k3t, Tt, n0, n1);
                msgT_kernel<<<1280, 256, 0, stream>>>(h2s, Tt, Bb, cnt, edgeStart,
                                                      dstS, agg, n0, n1);
            }
            update_kernel<<<NNODE / 8, 256, 0, stream>>>(hcur, hnext, agg, deg, rootw, convb,
                                                         k3b, Bb);
            float* tmp = hcur; hcur = hnext; hnext = tmp;
        }
    } else {
        // ================= fallback: fused-recompute path =================
        f16* h2b = (f16*)(ws + fixed);
        pack_k3<<<1280, 256, 0, stream>>>(k3w, k3p);

        long long availC = 0;
        if (ws_size > fixed) availC = (long long)((ws_size - fixed) / 512);
        int C = (availC > NEDGE) ? NEDGE : (int)availC;
        C &= ~255;
        if (C < 256) return;

        const bool full = (C == NEDGE);
        if (full)
            h2_kernel<<<NEDGE / 64, 256, 0, stream>>>(ea, k1p, k1b, k2p, k2b, h2b, 0, nullptr);

        for (int d = 0; d < 4; ++d) {
            for (int es = 0; es < NEDGE; es += C) {
                int ce = (NEDGE - es < C) ? (NEDGE - es) : C;
                if (!full)
                    h2_kernel<<<ce / 64, 256, 0, stream>>>(ea, k1p, k1b, k2p, k2b, h2b, es, nullptr);
                msg_fused<<<ce / 256, 256, 0, stream>>>(ei, h2b, k3p, k3b, hcur, agg, es);
            }
            update_fb_kernel<<<NNODE / 8, 256, 0, stream>>>(hcur, hnext, agg, deg, rootw, convb);
            float* tmp = hcur; hcur = hnext; hnext = tmp;
        }
    }
    out_kernel<<<(NNODE + 255) / 256, 256, 0, stream>>>(hcur, fc2w, fc2b, out);
}

// Round 15
// 609.828 us; speedup vs baseline: 1.0204x; 1.0204x over previous
//
#include <hip/hip_runtime.h>
#include <hip/hip_fp16.h>

#define NNODE 10000
#define NEDGE 160000
#define W32 32
#define BSTR 40          // f16 row stride for B panels (80 B, 16B-aligned)
#define PANEL_F16 10240  // h2 panels: 256 cols * 40
#define PANEL3_F16 5120  // msg panels: 128 cols * 40
#define UB_TILES 20000   // sum ceil(deg/16) <= E/16 + N = 20000
#define HB_STR 264       // hbuf f16 stride
#define TB_STR 1036      // tgen tile f16 stride

typedef _Float16 f16;
typedef _Float16 f16x4 __attribute__((ext_vector_type(4)));
typedef _Float16 f16x8 __attribute__((ext_vector_type(8)));
typedef float f32x4 __attribute__((ext_vector_type(4)));

// ---- stage one 20480-B panel (1280 slots) with 4 waves (256 thr) ----
__device__ __forceinline__ void stage_panel(f16* lds, const f16* g, int w, int lane) {
    #pragma unroll
    for (int i = 0; i < 5; ++i) {
        int slot = w * 320 + i * 64 + lane;
        __builtin_amdgcn_global_load_lds(
            (const __attribute__((address_space(1))) unsigned int*)(g + (size_t)slot * 8),
            (__attribute__((address_space(3))) unsigned int*)(lds + (size_t)(w * 320 + i * 64) * 8),
            16, 0, 0);
    }
}

// ---- stage one 10240-B panel (640 slots): 4 waves (fallback msg_fused) ----
__device__ __forceinline__ void stage_panel10k(f16* lds, const f16* g, int w, int lane) {
    #pragma unroll
    for (int i = 0; i < 2; ++i) {
        int base = i * 256 + w * 64;
        __builtin_amdgcn_global_load_lds(
            (const __attribute__((address_space(1))) unsigned int*)(g + (size_t)(base + lane) * 8),
            (__attribute__((address_space(3))) unsigned int*)(lds + (size_t)base * 8),
            16, 0, 0);
    }
    if (w < 2) {
        int base = 512 + w * 64;
        __builtin_amdgcn_global_load_lds(
            (const __attribute__((address_space(1))) unsigned int*)(g + (size_t)(base + lane) * 8),
            (__attribute__((address_space(3))) unsigned int*)(lds + (size_t)base * 8),
            16, 0, 0);
    }
}

// ================= weight packs =================
__global__ __launch_bounds__(256) void pack_k1(const float* __restrict__ k1w, f16* __restrict__ k1p) {
    int t = blockIdx.x * 256 + threadIdx.x;           // 10240
    int j = t / BSTR, c = t % BSTR;
    k1p[t] = (c < 6) ? (f16)k1w[c * 256 + j] : (f16)0.f;
}
__global__ __launch_bounds__(256) void pack_k2(const float* __restrict__ k2w, f16* __restrict__ k2p) {
    int t = blockIdx.x * 256 + threadIdx.x;           // 8*10240
    int kk = t / PANEL_F16, r = t % PANEL_F16;
    int j = r / BSTR, c = r % BSTR;
    k2p[t] = (c < 32) ? (f16)k2w[(size_t)(kk * 32 + c) * 256 + j] : (f16)0.f;
}
// fallback: k3 panels of 128 cols
__global__ __launch_bounds__(256) void pack_k3(const float* __restrict__ k3w, f16* __restrict__ k3p) {
    int t = blockIdx.x * 256 + threadIdx.x;           // 64*5120
    int p = t / PANEL3_F16, r = t % PANEL3_F16;
    int np = p >> 3, kk = p & 7;
    int j = r / BSTR, c = r % BSTR;
    k3p[t] = (c < 32) ? (f16)k3w[(size_t)(kk * 32 + c) * 1024 + np * 128 + j] : (f16)0.f;
}
// T-path: k3t[q'][i] = k3[c][i*32+o] with q' = o*256 + c  (8192 rows x BSTR)
__global__ __launch_bounds__(256) void pack_k3t(const float* __restrict__ k3w, f16* __restrict__ k3t) {
    int t = blockIdx.x * 256 + threadIdx.x;           // 327680
    int q = t / BSTR, i = t % BSTR;
    int o = q >> 8, c = q & 255;
    k3t[t] = (i < 32) ? (f16)k3w[(size_t)c * 1024 + i * 32 + o] : (f16)0.f;
}

// ================= h2 = relu(relu(ea@k1+b1)@k2+b2), fp16 out =================
// v6 (round-10 proven): dbuf panels + scattered epilogue + layer-2 wave-pair split.
__global__ __launch_bounds__(256) void h2_kernel(
    const float* __restrict__ ea,
    const f16* __restrict__ k1p, const float* __restrict__ k1b,
    const f16* __restrict__ k2p, const float* __restrict__ k2b,
    f16* __restrict__ h2c, int e_start, const int* __restrict__ remap)
{
    __shared__ __align__(16) f16 bls[2][256 * BSTR];  // 40 KB
    __shared__ __align__(16) f16 ea_s[64 * BSTR];     // 5 KB
    __shared__ __align__(16) f16 hbuf[64 * HB_STR];   // 33 KB -> 78 KB total, 2 blocks/CU

    const int t = threadIdx.x, w = t >> 6, lane = t & 63, quad = lane >> 4, l15 = lane & 15;
    const int el0 = blockIdx.x * 64;
    const int e0 = e_start + el0;

    stage_panel(bls[0], k1p, w, lane);                // k1 panel into b0
    for (int i = t; i < 64 * BSTR; i += 256) {
        int e = i / BSTR, c = i % BSTR;
        ea_s[i] = (f16)((c < 6) ? ea[(size_t)(e0 + e) * 6 + c] : 0.f);
    }
    __syncthreads();                                  // b0 + ea_s ready

    // ---- layer 1: wave w owns rows w*16..+15, all 256 cols ----
    f16x8 a1 = *(const f16x8*)&ea_s[(w * 16 + l15) * BSTR + quad * 8];
    {
        f32x4 acc1[16];
        #pragma unroll
        for (int nt = 0; nt < 16; ++nt) { float b = k1b[nt * 16 + l15]; acc1[nt] = (f32x4){b, b, b, b}; }
        stage_panel(bls[1], k2p, w, lane);            // k2 panel 0 into b1 (overlaps k1 MFMAs)
        #pragma unroll
        for (int nt = 0; nt < 16; ++nt) {
            f16x8 bf = *(const f16x8*)&bls[0][(nt * 16 + l15) * BSTR + quad * 8];
            acc1[nt] = __builtin_amdgcn_mfma_f32_16x16x32_f16(a1, bf, acc1[nt], 0, 0, 0);
        }
        #pragma unroll
        for (int nt = 0; nt < 16; ++nt)
            #pragma unroll
            for (int r = 0; r < 4; ++r)
                hbuf[(w * 16 + quad * 4 + r) * HB_STR + nt * 16 + l15] = (f16)fmaxf(acc1[nt][r], 0.f);
    }
    __syncthreads();                                  // hbuf (all rows) + b1 ready; b0 free

    // ---- layer 2: wave w -> row-half mh = w&1 (32 rows), col-half nh = w>>1 (128 cols) ----
    const int mh = w & 1, nh = w >> 1;
    f16x8 a2[2][8];
    #pragma unroll
    for (int m = 0; m < 2; ++m)
        #pragma unroll
        for (int kk = 0; kk < 8; ++kk)
            a2[m][kk] = *(const f16x8*)&hbuf[(mh * 32 + m * 16 + l15) * HB_STR + kk * 32 + quad * 8];
    f32x4 acc[2][8];
    #pragma unroll
    for (int nt = 0; nt < 8; ++nt) {
        float b = k2b[nh * 128 + nt * 16 + l15];
        acc[0][nt] = (f32x4){b, b, b, b};
        acc[1][nt] = (f32x4){b, b, b, b};
    }
    for (int kk = 0; kk < 8; ++kk) {
        if (kk < 7)
            stage_panel(bls[kk & 1], k2p + (size_t)(kk + 1) * PANEL_F16, w, lane);
        const f16* B = bls[(kk + 1) & 1];             // panel kk
        #pragma unroll
        for (int nt = 0; nt < 8; ++nt) {
            f16x8 bf = *(const f16x8*)&B[(nh * 128 + nt * 16 + l15) * BSTR + quad * 8];
            acc[0][nt] = __builtin_amdgcn_mfma_f32_16x16x32_f16(a2[0][kk], bf, acc[0][nt], 0, 0, 0);
            acc[1][nt] = __builtin_amdgcn_mfma_f32_16x16x32_f16(a2[1][kk], bf, acc[1][nt], 0, 0, 0);
        }
        __syncthreads();
    }
    size_t orow[2][4];
    #pragma unroll
    for (int m = 0; m < 2; ++m)
        #pragma unroll
        for (int r = 0; r < 4; ++r) {
            int row = mh * 32 + m * 16 + quad * 4 + r;
            orow[m][r] = remap ? (size_t)remap[e0 + row] : (size_t)(el0 + row);
        }
    #pragma unroll
    for (int m = 0; m < 2; ++m)
        #pragma unroll
        for (int nt = 0; nt < 8; ++nt)
            #pragma unroll
            for (int r = 0; r < 4; ++r)
                h2c[orow[m][r] * 256 + nh * 128 + nt * 16 + l15] = (f16)fmaxf(acc[m][nt][r], 0.f);
}

// ================= sort by src (counting sort) + tile build (16-edge tiles) =================
__global__ __launch_bounds__(256) void hist_kernel(const int* __restrict__ ei, int* __restrict__ cnt) {
    int e = blockIdx.x * 256 + threadIdx.x;
    if (e < NEDGE) atomicAdd(&cnt[ei[e]], 1);
}
__global__ __launch_bounds__(256) void scan_kernel(
    const int* __restrict__ cnt, int* __restrict__ edgeStart,
    int* __restrict__ tileStartN, int* __restrict__ cursor)
{
    __shared__ int pE[256], pT[256];
    const int t = threadIdx.x;
    int se = 0, st = 0;
    for (int k = 0; k < 40; ++k) {
        int n = t * 40 + k;
        if (n < NNODE) { int c = cnt[n]; se += c; st += (c + 15) >> 4; }
    }
    pE[t] = se; pT[t] = st;
    __syncthreads();
    if (t == 0) {
        int aE = 0, aT = 0;
        for (int i = 0; i < 256; ++i) { int tE = pE[i], tT = pT[i]; pE[i] = aE; pT[i] = aT; aE += tE; aT += tT; }
        tileStartN[NNODE] = aT;
    }
    __syncthreads();
    int oE = pE[t], oT = pT[t];
    for (int k = 0; k < 40; ++k) {
        int n = t * 40 + k;
        if (n < NNODE) {
            edgeStart[n] = oE; cursor[n] = oE; tileStartN[n] = oT;
            int c = cnt[n]; oE += c; oT += (c + 15) >> 4;
        }
    }
}
__global__ __launch_bounds__(256) void scatter_kernel(
    const int* __restrict__ ei, int* __restrict__ cursor,
    int* __restrict__ dstS, int* __restrict__ sortpos)
{
    int e = blockIdx.x * 256 + threadIdx.x;
    if (e < NEDGE) {
        int s = ei[e];
        int p = atomicAdd(&cursor[s], 1);
        dstS[p] = ei[NEDGE + e];
        sortpos[e] = p;
    }
}
__global__ __launch_bounds__(256) void tiles_kernel(
    const int* __restrict__ cnt, const int* __restrict__ edgeStart, const int* __restrict__ tileStartN,
    int* __restrict__ tileNode, int* __restrict__ tileE0, int* __restrict__ tileCnt)
{
    int n = blockIdx.x * 256 + threadIdx.x;
    if (n < NNODE) {
        int d = cnt[n], t0 = tileStartN[n], e0 = edgeStart[n];
        for (int k = 0; k * 16 < d; ++k) {
            int rem = d - k * 16;
            tileNode[t0 + k] = n;
            tileE0[t0 + k] = e0 + k * 16;
            tileCnt[t0 + k] = rem < 16 ? rem : 16;
        }
    }
}

// ================= T-path per depth =================
// h0 + fused Bb: h[n,j] = x[n]*w[j]+b[j]; Bb[n,o] = sum_i h[n,i]*k3b[i*32+o]
__global__ __launch_bounds__(256) void h0_kernel(
    const float* __restrict__ x, const float* __restrict__ fc1w,
    const float* __restrict__ fc1b, float* __restrict__ h,
    const float* __restrict__ k3b, float* __restrict__ Bb)
{
    int idx = blockIdx.x * 256 + threadIdx.x;
    int n = idx >> 5, j = idx & 31;
    float hv = x[n] * fc1w[j] + fc1b[j];
    h[idx] = hv;
    float s = 0.f;
    #pragma unroll
    for (int i = 0; i < 32; ++i)
        s += __shfl(hv, i, 32) * k3b[i * 32 + j];
    Bb[idx] = s;
}

// Tt[(n-n0)][q'] = sum_i h[n,i] * k3t[q'][i] (round-6 proven version)
__global__ __launch_bounds__(256) void tgen_kernel(
    const float* __restrict__ h, const f16* __restrict__ k3t, f16* __restrict__ Tt,
    int n0, int n1)
{
    __shared__ __align__(16) f16 tbuf[16 * TB_STR];   // 33 KB

    const int t = threadIdx.x, w = t >> 6, lane = t & 63, quad = lane >> 4, l15 = lane & 15;
    const int nBase = n0 + blockIdx.x * 16;
    const int colBase = blockIdx.y * 1024;

    f16x8 a;
    #pragma unroll
    for (int i = 0; i < 8; ++i) a[i] = (f16)0.f;
    int node = nBase + l15;
    if (node < n1) {
        const float4* hp = (const float4*)(h + (size_t)node * 32) + quad * 2;
        float4 v0 = hp[0], v1 = hp[1];
        a[0] = (f16)v0.x; a[1] = (f16)v0.y; a[2] = (f16)v0.z; a[3] = (f16)v0.w;
        a[4] = (f16)v1.x; a[5] = (f16)v1.y; a[6] = (f16)v1.z; a[7] = (f16)v1.w;
    }
    f32x4 acc[16];
    #pragma unroll
    for (int nt = 0; nt < 16; ++nt) {
        f16x8 bf = *(const f16x8*)&k3t[(size_t)(colBase + w * 256 + nt * 16 + l15) * BSTR + quad * 8];
        acc[nt] = __builtin_amdgcn_mfma_f32_16x16x32_f16(a, bf, (f32x4){0.f, 0.f, 0.f, 0.f}, 0, 0, 0);
    }
    #pragma unroll
    for (int nt = 0; nt < 16; ++nt)
        #pragma unroll
        for (int r = 0; r < 4; ++r)
            tbuf[(quad * 4 + r) * TB_STR + w * 256 + nt * 16 + l15] = (f16)acc[nt][r];
    __syncthreads();
    {
        const int row = t >> 4, u = t & 15;
        const int nd = nBase + row;
        if (nd < n1) {
            f16* gdst = Tt + (size_t)(nd - n0) * 8192 + colBase;
            const f16* lsrc = &tbuf[row * TB_STR];
            #pragma unroll
            for (int j = 0; j < 8; ++j) {
                int p = u + 16 * j;
                *(f16x8*)(gdst + p * 8) = *(const f16x8*)(lsrc + p * 8);
            }
        }
    }
}

// per-tile MFMA contraction, ATOMIC variant (round-10/13 proven)
__global__ __launch_bounds__(256) void msgT_kernel(
    const f16* __restrict__ h2s, const f16* __restrict__ Tt, const float* __restrict__ Bb,
    const int* __restrict__ tileNode, const int* __restrict__ tileE0, const int* __restrict__ tileCnt,
    const int* __restrict__ tileStartN, const int* __restrict__ dstS, float* __restrict__ agg,
    int n0, int n1)
{
    const int t = threadIdx.x, w = t >> 6, lane = t & 63, quad = lane >> 4, l15 = lane & 15;
    const int t0 = tileStartN[n0], t1 = tileStartN[n1];
    for (int tile = t0 + blockIdx.x * 4 + w; tile < t1; tile += gridDim.x * 4) {
        int n = tileNode[tile];
        int e0 = tileE0[tile], cnt = tileCnt[tile];
        const f16* Tn = Tt + (size_t)(n - n0) * 8192;
        f32x4 acc[2];
        #pragma unroll
        for (int nt = 0; nt < 2; ++nt) {
            float b = Bb[n * 32 + nt * 16 + l15];
            acc[nt] = (f32x4){b, b, b, b};
        }
        #pragma unroll
        for (int kk = 0; kk < 8; ++kk) {
            f16x8 a;
            #pragma unroll
            for (int i = 0; i < 8; ++i) a[i] = (f16)0.f;
            if (l15 < cnt)
                a = *(const f16x8*)&h2s[(size_t)(e0 + l15) * 256 + kk * 32 + quad * 8];
            #pragma unroll
            for (int nt = 0; nt < 2; ++nt) {
                f16x8 bf = *(const f16x8*)&Tn[(nt * 16 + l15) * 256 + kk * 32 + quad * 8];
                acc[nt] = __builtin_amdgcn_mfma_f32_16x16x32_f16(a, bf, acc[nt], 0, 0, 0);
            }
        }
        #pragma unroll
        for (int nt = 0; nt < 2; ++nt)
            #pragma unroll
            for (int r = 0; r < 4; ++r) {
                int er = quad * 4 + r;
                if (er < cnt)
                    atomicAdd(&agg[(size_t)dstS[e0 + er] * 32 + nt * 16 + l15], acc[nt][r]);
            }
    }
}

// ========== fallback: fused W-recompute + contract + scatter ==========
__global__ __launch_bounds__(256, 2) void msg_fused(
    const int* __restrict__ ei, const f16* __restrict__ h2c,
    const f16* __restrict__ k3p, const float* __restrict__ k3b,
    const float* __restrict__ h, float* __restrict__ agg, int e_start)
{
    __shared__ __align__(16) f16 bls[2][PANEL3_F16];
    __shared__ __align__(16) f16 h_s[256 * 36];
    __shared__ int dst_s[256];

    const int t = threadIdx.x, w = t >> 6, lane = t & 63, quad = lane >> 4, l15 = lane & 15;
    const int el0 = blockIdx.x * 256;
    const int e0 = e_start + el0;

    dst_s[t] = ei[NEDGE + e0 + t];
    {
        int srcn = ei[e0 + t];
        const float4* hr = (const float4*)(h + (size_t)srcn * 32);
        f16* dp = &h_s[t * 36];
        #pragma unroll
        for (int qq = 0; qq < 8; ++qq) {
            float4 v = hr[qq];
            dp[qq * 4 + 0] = (f16)v.x; dp[qq * 4 + 1] = (f16)v.y;
            dp[qq * 4 + 2] = (f16)v.z; dp[qq * 4 + 3] = (f16)v.w;
        }
    }
    stage_panel10k(bls[0], k3p, w, lane);

    float msg[4][4][2];
    #pragma unroll
    for (int m = 0; m < 4; ++m)
        #pragma unroll
        for (int r = 0; r < 4; ++r) { msg[m][r][0] = 0.f; msg[m][r][1] = 0.f; }

    f32x4 acc[4][8];
    __syncthreads();

    for (int it = 0; it < 64; ++it) {
        const int np = it >> 3, kk = it & 7;
        if (it) __syncthreads();
        if (it < 63) stage_panel10k(bls[(it + 1) & 1], k3p + (size_t)(it + 1) * PANEL3_F16, w, lane);

        f16x8 a[4];
        #pragma unroll
        for (int m = 0; m < 4; ++m)
            a[m] = *(const f16x8*)(h2c + (size_t)(el0 + w * 64 + m * 16 + l15) * 256 + kk * 32 + quad * 8);

        if (kk == 0) {
            #pragma unroll
            for (int nt = 0; nt < 8; ++nt) {
                float b = k3b[np * 128 + nt * 16 + l15];
                #pragma unroll
                for (int m = 0; m < 4; ++m) acc[m][nt] = (f32x4){b, b, b, b};
            }
        }
        const f16* B = bls[it & 1];
        #pragma unroll
        for (int nt = 0; nt < 8; ++nt) {
            f16x8 bf = *(const f16x8*)&B[(nt * 16 + l15) * BSTR + quad * 8];
            #pragma unroll
            for (int m = 0; m < 4; ++m)
                acc[m][nt] = __builtin_amdgcn_mfma_f32_16x16x32_f16(a[m], bf, acc[m][nt], 0, 0, 0);
        }
        if (kk == 7) {
            #pragma unroll
            for (int m = 0; m < 4; ++m)
                #pragma unroll
                for (int r = 0; r < 4; ++r) {
                    int row = w * 64 + m * 16 + quad * 4 + r;
                    f16x4 h4 = *(const f16x4*)&h_s[row * 36 + np * 4];
                    #pragma unroll
                    for (int nt = 0; nt < 8; ++nt)
                        msg[m][r][nt & 1] += (float)h4[nt >> 1] * acc[m][nt][r];
                }
        }
    }
    #pragma unroll
    for (int m = 0; m < 4; ++m)
        #pragma unroll
        for (int r = 0; r < 4; ++r) {
            int d = dst_s[w * 64 + m * 16 + quad * 4 + r];
            atomicAdd(&agg[d * W32 + l15],      msg[m][r][0]);
            atomicAdd(&agg[d * W32 + 16 + l15], msg[m][r][1]);
        }
}

// ================= small kernels =================
__global__ __launch_bounds__(256) void deg_kernel(
    const int* __restrict__ ei, float* __restrict__ deg)
{
    int e = blockIdx.x * 256 + threadIdx.x;
    if (e < NEDGE) atomicAdd(&deg[ei[NEDGE + e]], 1.f);
}

// update + fused Bb for the NEXT depth
__global__ __launch_bounds__(256) void update_kernel(
    const float* __restrict__ h_old, float* __restrict__ h_new,
    float* __restrict__ agg, const float* __restrict__ deg,
    const float* __restrict__ rootw, const float* __restrict__ convb,
    const float* __restrict__ k3b, float* __restrict__ Bb)
{
    __shared__ float rw[W32][W32 + 1];
    const int t = threadIdx.x;
    for (int q = t; q < W32 * W32; q += 256)
        rw[q >> 5][q & 31] = rootw[q];
    __syncthreads();
    const int nl = t >> 5, j = t & 31;
    const int n = blockIdx.x * 8 + nl;
    float hv = h_old[n * W32 + j];
    float acc = convb[j];
    #pragma unroll
    for (int k = 0; k < W32; ++k)
        acc += __shfl(hv, k, 32) * rw[k][j];
    float inv = 1.f / fmaxf(deg[n], 1.f);
    int idx = n * W32 + j;
    float a = agg[idx];
    agg[idx] = 0.f;
    float hn = fmaxf(a * inv + acc, 0.f);
    h_new[idx] = hn;
    float s = 0.f;
    #pragma unroll
    for (int i = 0; i < 32; ++i)
        s += __shfl(hn, i, 32) * k3b[i * 32 + j];
    Bb[idx] = s;
}

// fallback update (no Bb fusion)
__global__ __launch_bounds__(256) void update_fb_kernel(
    const float* __restrict__ h_old, float* __restrict__ h_new,
    float* __restrict__ agg, const float* __restrict__ deg,
    const float* __restrict__ rootw, const float* __restrict__ convb)
{
    __shared__ float rw[W32][W32 + 1];
    const int t = threadIdx.x;
    for (int q = t; q < W32 * W32; q += 256)
        rw[q >> 5][q & 31] = rootw[q];
    __syncthreads();
    const int nl = t >> 5, j = t & 31;
    const int n = blockIdx.x * 8 + nl;
    float hv = h_old[n * W32 + j];
    float acc = convb[j];
    #pragma unroll
    for (int k = 0; k < W32; ++k)
        acc += __shfl(hv, k, 32) * rw[k][j];
    float inv = 1.f / fmaxf(deg[n], 1.f);
    int idx = n * W32 + j;
    float a = agg[idx];
    agg[idx] = 0.f;
    h_new[idx] = fmaxf(a * inv + acc, 0.f);
}

__global__ __launch_bounds__(256) void out_kernel(
    const float* __restrict__ h, const float* __restrict__ fc2w,
    const float* __restrict__ fc2b, float* __restrict__ out)
{
    int n = blockIdx.x * 256 + threadIdx.x;
    if (n < NNODE) {
        float a = fc2b[0];
        #pragma unroll
        for (int j = 0; j < W32; ++j)
            a += h[n * W32 + j] * fc2w[j];
        out[n] = a;
    }
}

static inline size_t pad256(size_t x) { return (x + 255) & ~(size_t)255; }

extern "C" void kernel_launch(void* const* d_in, const int* in_sizes, int n_in,
                              void* d_out, int out_size, void* d_ws, size_t ws_size,
                              hipStream_t stream) {
    const float* x    = (const float*)d_in[0];
    const int*   ei   = (const int*)  d_in[1];
    const float* ea   = (const float*)d_in[2];
    const float* fc1w = (const float*)d_in[3];
    const float* fc1b = (const float*)d_in[4];
    const float* k1w  = (const float*)d_in[5];
    const float* k1b  = (const float*)d_in[6];
    const float* k2w  = (const float*)d_in[7];
    const float* k2b  = (const float*)d_in[8];
    const float* k3w  = (const float*)d_in[9];
    const float* k3b  = (const float*)d_in[10];
    const float* rootw= (const float*)d_in[11];
    const float* convb= (const float*)d_in[12];
    const float* fc2w = (const float*)d_in[13];
    const float* fc2b = (const float*)d_in[14];
    float* out = (float*)d_out;

    const size_t hbytes = (size_t)NNODE * W32 * 4;
    char* ws = (char*)d_ws;
    size_t off = 0;
    float* hA  = (float*)(ws + off); off += hbytes;
    float* hB  = (float*)(ws + off); off += hbytes;
    float* agg = (float*)(ws + off); off += hbytes;
    float* deg = (float*)(ws + off); off += 40960;
    f16*  k1p  = (f16*)(ws + off);   off += 20480;
    f16*  k2p  = (f16*)(ws + off);   off += 163840;
    f16*  k3p  = (f16*)(ws + off);   off += 655360;
    const size_t fixed = off;

    // ---- T-path layout ----
    size_t toff = fixed;
    f16*  k3t      = (f16*)(ws + toff);  toff += pad256(8192 * BSTR * 2);
    int*  dstS     = (int*)(ws + toff);  toff += pad256((size_t)NEDGE * 4);
    int*  sortpos  = (int*)(ws + toff);  toff += pad256((size_t)NEDGE * 4);
    int*  cnt      = (int*)(ws + toff);  toff += pad256((size_t)NNODE * 4);
    int*  edgeStart= (int*)(ws + toff);  toff += pad256((size_t)NNODE * 4);
    int*  tileStartN=(int*)(ws + toff);  toff += pad256((size_t)(NNODE + 1) * 4);
    int*  cursor   = (int*)(ws + toff);  toff += pad256((size_t)NNODE * 4);
    int*  tileNode = (int*)(ws + toff);  toff += pad256((size_t)UB_TILES * 4);
    int*  tileE0   = (int*)(ws + toff);  toff += pad256((size_t)UB_TILES * 4);
    int*  tileCnt  = (int*)(ws + toff);  toff += pad256((size_t)UB_TILES * 4);
    float* Bb      = (float*)(ws + toff); toff += pad256((size_t)NNODE * 32 * 4);
    f16*  h2s      = (f16*)(ws + toff);  toff += pad256((size_t)NEDGE * 256 * 2);
    f16*  Tt       = (f16*)(ws + toff);

    // nc=1 preferred (round-3/4 A/B: Tt+h2s fits L3; splitting regressed)
    int nc = 0, CS = 0;
    {
        const int cands[4] = {1, 2, 4, 8};
        for (int ci = 0; ci < 4; ++ci) {
            int c = cands[ci];
            int cs = ((NNODE + c - 1) / c + 15) & ~15;
            size_t tb = (size_t)cs * 8192 * 2;
            if (ws_size >= toff + tb) { nc = c; CS = cs; break; }
        }
    }

    hipMemsetAsync(deg, 0, (size_t)NNODE * 4, stream);
    hipMemsetAsync(agg, 0, (size_t)NNODE * W32 * 4, stream);

    pack_k1<<<40, 256, 0, stream>>>(k1w, k1p);
    pack_k2<<<320, 256, 0, stream>>>(k2w, k2p);

    h0_kernel<<<NNODE * W32 / 256, 256, 0, stream>>>(x, fc1w, fc1b, hA, k3b, Bb);
    deg_kernel<<<(NEDGE + 255) / 256, 256, 0, stream>>>(ei, deg);

    float* hcur = hA; float* hnext = hB;

    if (nc) {
        // ================= T-path =================
        pack_k3t<<<1280, 256, 0, stream>>>(k3w, k3t);
        hipMemsetAsync(cnt, 0, (size_t)NNODE * 4, stream);
        hist_kernel<<<(NEDGE + 255) / 256, 256, 0, stream>>>(ei, cnt);
        scan_kernel<<<1, 256, 0, stream>>>(cnt, edgeStart, tileStartN, cursor);
        scatter_kernel<<<(NEDGE + 255) / 256, 256, 0, stream>>>(ei, cursor, dstS, sortpos);
        tiles_kernel<<<(NNODE + 255) / 256, 256, 0, stream>>>(cnt, edgeStart, tileStartN,
                                                              tileNode, tileE0, tileCnt);
        h2_kernel<<<NEDGE / 64, 256, 0, stream>>>(ea, k1p, k1b, k2p, k2b, h2s, 0, sortpos);

        for (int d = 0; d < 4; ++d) {
            // Bb for this depth was produced by h0 (d=0) or the previous update (d>0)
            for (int ct = 0; ct < nc; ++ct) {
                int n0 = ct * CS;
                if (n0 >= NNODE) break;
                int n1 = n0 + CS; if (n1 > NNODE) n1 = NNODE;
                dim3 tg((n1 - n0 + 15) / 16, 8);
                tgen_kernel<<<tg, 256, 0, stream>>>(hcur, k3t, Tt, n0, n1);
                msgT_kernel<<<1280, 256, 0, stream>>>(h2s, Tt, Bb, tileNode, tileE0, tileCnt,
                                                      tileStartN, dstS, agg, n0, n1);
            }
            update_kernel<<<NNODE / 8, 256, 0, stream>>>(hcur, hnext, agg, deg, rootw, convb,
                                                         k3b, Bb);
            float* tmp = hcur; hcur = hnext; hnext = tmp;
        }
    } else {
        // ================= fallback: fused-recompute path =================
        f16* h2b = (f16*)(ws + fixed);
        pack_k3<<<1280, 256, 0, stream>>>(k3w, k3p);

        long long availC = 0;
        if (ws_size > fixed) availC = (long long)((ws_size - fixed) / 512);
        int C = (availC > NEDGE) ? NEDGE : (int)availC;
        C &= ~255;
        if (C < 256) return;

        const bool full = (C == NEDGE);
        if (full)
            h2_kernel<<<NEDGE / 64, 256, 0, stream>>>(ea, k1p, k1b, k2p, k2b, h2b, 0, nullptr);

        for (int d = 0; d < 4; ++d) {
            for (int es = 0; es < NEDGE; es += C) {
                int ce = (NEDGE - es < C) ? (NEDGE - es) : C;
                if (!full)
                    h2_kernel<<<ce / 64, 256, 0, stream>>>(ea, k1p, k1b, k2p, k2b, h2b, es, nullptr);
                msg_fused<<<ce / 256, 256, 0, stream>>>(ei, h2b, k3p, k3b, hcur, agg, es);
            }
            update_fb_kernel<<<NNODE / 8, 256, 0, stream>>>(hcur, hnext, agg, deg, rootw, convb);
            float* tmp = hcur; hcur = hnext; hnext = tmp;
        }
    }
    out_kernel<<<(NNODE + 255) / 256, 256, 0, stream>>>(hcur, fc2w, fc2b, out);
}